// Round 14
// baseline (296.189 us; speedup 1.0000x reference)
//
#include <hip/hip_runtime.h>
#include <hip/hip_bf16.h>
#include <hip/hip_fp16.h>

typedef unsigned short u16;
typedef __attribute__((ext_vector_type(8))) _Float16 f16x8;  // 8 fp16 = 4 VGPR
typedef __attribute__((ext_vector_type(4))) float f32x4;     // MFMA 16x16 acc

#define B_ 8
#define S_ 2048
#define H_ 1024
#define M_ (B_ * S_)   // 16384

__device__ __forceinline__ u16 f2h(float f) {
  _Float16 h = (_Float16)f;
  return __builtin_bit_cast(u16, h);
}

// ---------- convert fp32 -> fp16 (W only) ----------
__global__ void f32_to_f16_kernel(const float* __restrict__ x,
                                  u16* __restrict__ o, int n4) {
  int stride = gridDim.x * blockDim.x;
  for (int i = blockIdx.x * blockDim.x + threadIdx.x; i < n4; i += stride) {
    float4 v = reinterpret_cast<const float4*>(x)[i];
    ushort4 h;
    h.x = f2h(v.x); h.y = f2h(v.y); h.z = f2h(v.z); h.w = f2h(v.w);
    reinterpret_cast<ushort4*>(o)[i] = h;
  }
}

// ---------- fused: X fp32 [b][s][h] -> XT fp16 [b][h][s] AND XF fp16 -------
// r14: write phase restructured for coalescing — each 16-lane group writes
// a contiguous 128B span of ONE XT row (4 row-segments/wave vs r13's 64
// scattered 32B chunks at stride 4KB). LDS pad 66 u16 -> gather bank
// stride 4 (2-way alias, free per m136).
__global__ __launch_bounds__(256) void transpose_f32_kernel(
    const float* __restrict__ x, u16* __restrict__ xt, u16* __restrict__ xf) {
  __shared__ u16 t[64][66];
  int b = blockIdx.z, s0 = blockIdx.x * 64, h0 = blockIdx.y * 64;
  int tid = threadIdx.x;
  // read phase: row = s-offset (coalesced float4), seg covers 16 h each
  int row = tid & 63, seg = tid >> 6;  // 4 segs x 16 elems
  const float* src = x + ((size_t)(b * S_ + s0 + row)) * H_ + h0 + seg * 16;
  u16* dstf = xf + ((size_t)(b * S_ + s0 + row)) * H_ + h0 + seg * 16;
#pragma unroll
  for (int j = 0; j < 4; ++j) {
    float4 v = reinterpret_cast<const float4*>(src)[j];
    ushort4 h;
    h.x = f2h(v.x); h.y = f2h(v.y); h.z = f2h(v.z); h.w = f2h(v.w);
    reinterpret_cast<ushort4*>(dstf)[j] = h;
    *reinterpret_cast<ushort4*>(&t[row][seg * 16 + j * 4]) = h;
  }
  __syncthreads();
  // write phase: lane group (tid>>4) owns XT row hh; 16 lanes span 64 s.
  int hq = tid >> 4;        // 0..15
  int sq = (tid & 15) * 4;  // s-quad 0..60
#pragma unroll
  for (int it = 0; it < 4; ++it) {
    int hh = it * 16 + hq;
    ushort4 o;
    o.x = t[sq + 0][hh];
    o.y = t[sq + 1][hh];
    o.z = t[sq + 2][hh];
    o.w = t[sq + 3][hh];
    u16* dst = xt + ((size_t)(b * H_ + h0 + hh)) * S_ + s0 + sq;
    *reinterpret_cast<ushort4*>(dst) = o;
  }
}

// ---------- async global->LDS 16B ----------
__device__ __forceinline__ void async_stage16(const u16* g, u16* l) {
  __builtin_amdgcn_global_load_lds(
      (__attribute__((address_space(1))) void*)g,
      (__attribute__((address_space(3))) void*)l, 16, 0, 0);
}

// ---------- 256x256x64 4-phase fp16 BT-GEMM (r11, proven) -----------------
// C[m,n] = sum_k A[m,k]*B[n,k]; 512 thr / 8 waves (2M x 4N); LDS 2 slots x
// (A+B half-tiles) = 128 KB; XOR-swizzle byte^((row&7)<<4) src + reads.
// Read-ahead pipeline (dual fragment sets), one closing barrier per phase,
// stages into barrier-separated dead regions, single VM6/tile after MFMA.
template <int OM>  // 0: fp32 out; 1: fp16 out + bias
__global__ __launch_bounds__(512) void gemm8_kernel(
    const u16* __restrict__ A, const u16* __restrict__ B,
    float* __restrict__ Cf, u16* __restrict__ Ch,
    const float* __restrict__ bias,
    int lda, int ldb, int ldc, int K,
    long sAz, long sBz, long sCz) {
  __shared__ __align__(16) u16 sA[2][256 * 64];
  __shared__ __align__(16) u16 sB[2][256 * 64];

  // ---- XCD swizzle (T1, bijective m204) ----
  int gx = gridDim.x, gy = gridDim.y;
  int nwg = gx * gy * gridDim.z;
  int wgid = blockIdx.x + gx * (blockIdx.y + gy * blockIdx.z);
  int q = nwg >> 3, r = nwg & 7;
  int xcd = wgid & 7, idx = wgid >> 3;
  int nid = (xcd < r ? xcd * (q + 1) : r * (q + 1) + (xcd - r) * q) + idx;
  int bxi = nid % gx, t2 = nid / gx;
  int byi = t2 % gy, bzi = t2 / gy;

  int tid = threadIdx.x, wave = tid >> 6, lane = tid & 63;
  int wm = wave >> 2, wn = wave & 3;
  int bm = bxi * 256, bn = byi * 256;
  long zA = (long)bzi * sAz;
  long zB = (long)bzi * sBz;
  long zC = (long)bzi * sCz;
  const u16* gA = A + zA + (size_t)bm * lda;
  const u16* gB = B + zB + (size_t)bn * ldb;

  // staging constants: thread -> (row srow/srow+64, byte col scolb) of a half
  int srow = tid >> 3;             // 0..63
  int scolb = (tid & 7) << 4;      // 0..112
  int sco = (scolb ^ ((srow & 7) << 4)) >> 1;  // swizzled src col (u16)
  size_t aO0 = (size_t)srow * lda + sco, aO1 = aO0 + (size_t)64 * lda;
  size_t bO0 = (size_t)srow * ldb + sco, bO1 = bO0 + (size_t)64 * ldb;
  int ld0 = srow * 64 + (scolb >> 1), ld1 = ld0 + 64 * 64;

  auto stgA = [&](int slot, int half, int kofs) {
    const u16* g = gA + (size_t)(half * 128) * lda + kofs;
    u16* l = &sA[slot][half * 8192];
    async_stage16(g + aO0, l + ld0);
    async_stage16(g + aO1, l + ld1);
  };
  auto stgB = [&](int slot, int half, int kofs) {
    const u16* g = gB + (size_t)(half * 128) * ldb + kofs;
    u16* l = &sB[slot][half * 8192];
    async_stage16(g + bO0, l + ld0);
    async_stage16(g + bO1, l + ld1);
  };

  // fragment reads (swizzled)
  int la = lane & 15;
  int kg = (lane >> 4) << 4;
  auto frag = [&](const u16* base, int row, int colb) -> f16x8 {
    int off = (row << 7) + (colb ^ ((row & 7) << 4));
    return *reinterpret_cast<const f16x8*>(
        reinterpret_cast<const char*>(base) + off);
  };

  // dual fragment sets (read-ahead pipeline)
  f16x8 aF0[4][2], aF1[4][2];  // A half 0 / half 1
  f16x8 bF0[2][2], bF1[2][2];  // B half 0 / half 1
  f32x4 acc[8][4] = {};

  auto RA = [&](int slot, int qm, f16x8(&dst)[4][2]) {
#pragma unroll
    for (int j = 0; j < 4; ++j)
#pragma unroll
      for (int ks = 0; ks < 2; ++ks)
        dst[j][ks] = frag(sA[slot], qm * 128 + (j * 2 + wm) * 16 + la,
                          ks * 64 + kg);
  };
  auto RB = [&](int slot, int qn, f16x8(&dst)[2][2]) {
#pragma unroll
    for (int i = 0; i < 2; ++i)
#pragma unroll
      for (int ks = 0; ks < 2; ++ks)
        dst[i][ks] = frag(sB[slot], qn * 128 + (i * 4 + wn) * 16 + la,
                          ks * 64 + kg);
  };
  auto MM = [&](int qm, int qn, f16x8(&a)[4][2], f16x8(&b)[2][2]) {
#pragma unroll
    for (int ks = 0; ks < 2; ++ks)
#pragma unroll
      for (int j = 0; j < 4; ++j)
#pragma unroll
        for (int i = 0; i < 2; ++i)
          acc[qm * 4 + j][qn * 2 + i] = __builtin_amdgcn_mfma_f32_16x16x32_f16(
              a[j][ks], b[i][ks], acc[qm * 4 + j][qn * 2 + i], 0, 0, 0);
  };

#define VM6 asm volatile("s_waitcnt vmcnt(6)" ::: "memory")
#define VM0 asm volatile("s_waitcnt vmcnt(0)" ::: "memory")
#define BAR __builtin_amdgcn_s_barrier()
#define PRIO1 __builtin_amdgcn_s_setprio(1)
#define PRIO0 __builtin_amdgcn_s_setprio(0)

  int NT = K >> 6;  // K-tiles
  // prologue: T0 (A0,B0,B1,A1) -> slot0; T1's A0,B1,A1 -> slot1.
  stgA(0, 0, 0); stgB(0, 0, 0); stgB(0, 1, 0); stgA(0, 1, 0);
  if (NT > 1) { stgA(1, 0, 64); stgB(1, 1, 64); stgA(1, 1, 64); }
  VM6;
  BAR;

  for (int t = 0; t < NT; ++t) {
    int s = t & 1, ns = s ^ 1;
    int k1 = (t + 1) << 6, k2 = (t + 2) << 6;
    bool p1 = (t + 1 < NT), p2 = (t + 2 < NT);
    // ph1: read q00 frags + read-ahead bF1; stage B0(T+1)->ns
    RA(s, 0, aF0); RB(s, 0, bF0);
    RB(s, 1, bF1);
    if (p1) stgB(ns, 0, k1);
    PRIO1; MM(0, 0, aF0, bF0); PRIO0; BAR;
    // ph2: read-ahead aF1; stage A0(T+2)->s; MFMA q01
    RA(s, 1, aF1);
    if (p2) stgA(s, 0, k2);
    PRIO1; MM(0, 1, aF0, bF1); PRIO0; BAR;
    // ph3: stage B1(T+2)->s; MFMA q11
    if (p2) stgB(s, 1, k2);
    PRIO1; MM(1, 1, aF1, bF1); PRIO0; BAR;
    // ph4: stage A1(T+2)->s; MFMA q10; VM; BAR
    if (p2) stgA(s, 1, k2);
    PRIO1; MM(1, 0, aF1, bF0); PRIO0;
    if (t < NT - 2) { VM6; } else if (t == NT - 2) { VM0; }
    BAR;
  }
#undef VM6
#undef VM0
#undef BAR
#undef PRIO1
#undef PRIO0

  // Epilogue. C/D layout (16x16): col = lane&15, row = (lane>>4)*4 + reg.
#pragma unroll
  for (int mf = 0; mf < 8; ++mf) {
    int qm = mf >> 2, j = mf & 3;
    int row = bm + qm * 128 + (j * 2 + wm) * 16 + (lane >> 4) * 4;
#pragma unroll
    for (int nf = 0; nf < 4; ++nf) {
      int qn = nf >> 1, i = nf & 1;
      int col = bn + qn * 128 + (i * 4 + wn) * 16 + la;
#pragma unroll
      for (int r = 0; r < 4; ++r) {
        float v = acc[mf][nf][r];
        if constexpr (OM == 1) {
          Ch[zC + (size_t)(row + r) * ldc + col] = f2h(v + bias[col]);
        } else {
          Cf[zC + (size_t)(row + r) * ldc + col] = v;
        }
      }
    }
  }
}

// ---------- row softmax: fp32 [rows][2048] -> fp16 (pitch opitch u16) -----
__global__ __launch_bounds__(256) void softmax_kernel(const float* __restrict__ sc,
                                                      u16* __restrict__ attn,
                                                      int opitch) {
  __shared__ float red[4];
  size_t row = blockIdx.x;
  const float* p = sc + row * S_;
  u16* o = attn + row * (size_t)opitch;
  int t = threadIdx.x;
  float4 v0 = reinterpret_cast<const float4*>(p)[t];
  float4 v1 = reinterpret_cast<const float4*>(p)[t + 256];
  float mx = fmaxf(fmaxf(fmaxf(v0.x, v0.y), fmaxf(v0.z, v0.w)),
                   fmaxf(fmaxf(v1.x, v1.y), fmaxf(v1.z, v1.w)));
#pragma unroll
  for (int d = 32; d > 0; d >>= 1) mx = fmaxf(mx, __shfl_xor(mx, d));
  if ((t & 63) == 0) red[t >> 6] = mx;
  __syncthreads();
  mx = fmaxf(fmaxf(red[0], red[1]), fmaxf(red[2], red[3]));
  float e[8];
  e[0] = __expf(v0.x - mx); e[1] = __expf(v0.y - mx);
  e[2] = __expf(v0.z - mx); e[3] = __expf(v0.w - mx);
  e[4] = __expf(v1.x - mx); e[5] = __expf(v1.y - mx);
  e[6] = __expf(v1.z - mx); e[7] = __expf(v1.w - mx);
  float s = ((e[0] + e[1]) + (e[2] + e[3])) + ((e[4] + e[5]) + (e[6] + e[7]));
#pragma unroll
  for (int d = 32; d > 0; d >>= 1) s += __shfl_xor(s, d);
  __syncthreads();
  if ((t & 63) == 0) red[t >> 6] = s;
  __syncthreads();
  s = (red[0] + red[1]) + (red[2] + red[3]);
  float inv = 1.0f / s;
  ushort4 h0, h1;
  h0.x = f2h(e[0] * inv); h0.y = f2h(e[1] * inv);
  h0.z = f2h(e[2] * inv); h0.w = f2h(e[3] * inv);
  h1.x = f2h(e[4] * inv); h1.y = f2h(e[5] * inv);
  h1.z = f2h(e[6] * inv); h1.w = f2h(e[7] * inv);
  // all reads happened before the syncthreads above -> in-place safe
  reinterpret_cast<ushort4*>(o)[t] = h0;
  reinterpret_cast<ushort4*>(o)[t + 256] = h1;
}

extern "C" void kernel_launch(void* const* d_in, const int* in_sizes, int n_in,
                              void* d_out, int out_size, void* d_ws, size_t ws_size,
                              hipStream_t stream) {
  const float* X = (const float*)d_in[0];     // [8,2048,1024] fp32
  const float* W = (const float*)d_in[1];     // [1024,1024] fp32 (out,in)
  const float* bias = (const float*)d_in[2];  // [1024] fp32
  float* out = (float*)d_out;
  char* ws = (char*)d_ws;

  const size_t MB = 1ull << 20;
  u16* XF = (u16*)(ws);               // 32MB [16384][1024] fp16
  u16* WF = (u16*)(ws + 32 * MB);     // 2MB
  u16* XT = (u16*)(ws + 34 * MB);     // 32MB [b][1024][2048] fp16
  u16* QW = (u16*)(ws + 66 * MB);     // 32MB [16384][1024] fp16
  float* SC = (float*)(ws + 98 * MB); // CB*16MB fp32 scores (P in-place fp16)

  int CB = (ws_size >= 163 * MB) ? 4 : 2;
  int nch = B_ / CB;

  // 1) W -> fp16
  f32_to_f16_kernel<<<1024, 256, 0, stream>>>(W, WF, H_ * H_ / 4);
  // 2) fused: XF = fp16(X); XT[b][h][s] = fp16(X[b][s][h])
  transpose_f32_kernel<<<dim3(S_ / 64, H_ / 64, B_), 256, 0, stream>>>(
      X, XT, XF);
  // 3) QW = X @ W^T + b -> fp16
  gemm8_kernel<1><<<dim3(M_ / 256, H_ / 256, 1), 512, 0, stream>>>(
      XF, WF, nullptr, QW, bias, H_, H_, H_, H_, 0, 0, 0);
  // 4-6) per chunk: score -> softmax(in-place) -> PV
  for (int ch = 0; ch < nch; ++ch) {
    long off = (long)ch * CB;
    gemm8_kernel<0><<<dim3(S_ / 256, S_ / 256, CB), 512, 0, stream>>>(
        QW + off * S_ * H_, XF + off * S_ * H_, SC, nullptr, nullptr,
        H_, H_, S_, H_, (long)S_ * H_, (long)S_ * H_, (long)S_ * S_);
    softmax_kernel<<<CB * S_, 256, 0, stream>>>(SC, (u16*)SC, 2 * S_);
    gemm8_kernel<0><<<dim3(S_ / 256, H_ / 256, CB), 512, 0, stream>>>(
        (u16*)SC, XT + off * (long)H_ * S_,
        out + off * (long)S_ * H_, nullptr, nullptr,
        2 * S_, S_, H_, S_, (long)S_ * 2 * S_, (long)H_ * S_, (long)S_ * H_);
  }
}

// Round 15
// 264.307 us; speedup vs baseline: 1.1206x; 1.1206x over previous
//
#include <hip/hip_runtime.h>
#include <hip/hip_bf16.h>
#include <hip/hip_fp16.h>

typedef unsigned short u16;
typedef __attribute__((ext_vector_type(8))) _Float16 f16x8;  // 8 fp16 = 4 VGPR
typedef __attribute__((ext_vector_type(4))) float f32x4;     // MFMA 16x16 acc

#define B_ 8
#define S_ 2048
#define H_ 1024
#define M_ (B_ * S_)   // 16384

__device__ __forceinline__ u16 f2h(float f) {
  _Float16 h = (_Float16)f;
  return __builtin_bit_cast(u16, h);
}

// ---------- convert fp32 -> fp16 (W only) ----------
__global__ void f32_to_f16_kernel(const float* __restrict__ x,
                                  u16* __restrict__ o, int n4) {
  int stride = gridDim.x * blockDim.x;
  for (int i = blockIdx.x * blockDim.x + threadIdx.x; i < n4; i += stride) {
    float4 v = reinterpret_cast<const float4*>(x)[i];
    ushort4 h;
    h.x = f2h(v.x); h.y = f2h(v.y); h.z = f2h(v.z); h.w = f2h(v.w);
    reinterpret_cast<ushort4*>(o)[i] = h;
  }
}

// ---------- fused: X fp32 [b][s][h] -> XT fp16 [b][h][s] AND XF fp16 -------
// r14's coalesced version: write phase emits contiguous 128B spans of one
// XT row per 16-lane group (vs 4KB-stride scatter). LDS pad 66 u16 ->
// gather bank stride 4 (2-way alias, free per m136).
__global__ __launch_bounds__(256) void transpose_f32_kernel(
    const float* __restrict__ x, u16* __restrict__ xt, u16* __restrict__ xf) {
  __shared__ u16 t[64][66];
  int b = blockIdx.z, s0 = blockIdx.x * 64, h0 = blockIdx.y * 64;
  int tid = threadIdx.x;
  int row = tid & 63, seg = tid >> 6;  // 4 segs x 16 elems
  const float* src = x + ((size_t)(b * S_ + s0 + row)) * H_ + h0 + seg * 16;
  u16* dstf = xf + ((size_t)(b * S_ + s0 + row)) * H_ + h0 + seg * 16;
#pragma unroll
  for (int j = 0; j < 4; ++j) {
    float4 v = reinterpret_cast<const float4*>(src)[j];
    ushort4 h;
    h.x = f2h(v.x); h.y = f2h(v.y); h.z = f2h(v.z); h.w = f2h(v.w);
    reinterpret_cast<ushort4*>(dstf)[j] = h;
    *reinterpret_cast<ushort4*>(&t[row][seg * 16 + j * 4]) = h;
  }
  __syncthreads();
  int hq = tid >> 4;        // 0..15
  int sq = (tid & 15) * 4;  // s-quad 0..60
#pragma unroll
  for (int it = 0; it < 4; ++it) {
    int hh = it * 16 + hq;
    ushort4 o;
    o.x = t[sq + 0][hh];
    o.y = t[sq + 1][hh];
    o.z = t[sq + 2][hh];
    o.w = t[sq + 3][hh];
    u16* dst = xt + ((size_t)(b * H_ + h0 + hh)) * S_ + s0 + sq;
    *reinterpret_cast<ushort4*>(dst) = o;
  }
}

// ---------- async global->LDS 16B ----------
__device__ __forceinline__ void async_stage16(const u16* g, u16* l) {
  __builtin_amdgcn_global_load_lds(
      (__attribute__((address_space(1))) void*)g,
      (__attribute__((address_space(3))) void*)l, 16, 0, 0);
}

// ---------- 256x(NB*128)x64 fp16 BT-GEMM (r11 NB=2 + r13 NB=1, proven) ----
template <int OM, int NB>  // OM: 0 fp32 out; 1 fp16 out + bias
__global__ __launch_bounds__(512) void gemm8_kernel(
    const u16* __restrict__ A, const u16* __restrict__ B,
    float* __restrict__ Cf, u16* __restrict__ Ch,
    const float* __restrict__ bias,
    int lda, int ldb, int ldc, int K,
    long sAz, long sBz, long sCz) {
  __shared__ __align__(16) u16 sA[2][256 * 64];
  __shared__ __align__(16) u16 sB[2][NB * 128 * 64];

  // ---- XCD swizzle (T1, bijective m204) ----
  int gx = gridDim.x, gy = gridDim.y;
  int nwg = gx * gy * gridDim.z;
  int wgid = blockIdx.x + gx * (blockIdx.y + gy * blockIdx.z);
  int q = nwg >> 3, r = nwg & 7;
  int xcd = wgid & 7, idx = wgid >> 3;
  int nid = (xcd < r ? xcd * (q + 1) : r * (q + 1) + (xcd - r) * q) + idx;
  int bxi = nid % gx, t2 = nid / gx;
  int byi = t2 % gy, bzi = t2 / gy;

  int tid = threadIdx.x, wave = tid >> 6, lane = tid & 63;
  int wm = wave >> 2, wn = wave & 3;
  int bm = bxi * 256, bn = byi * (NB * 128);
  long zA = (long)bzi * sAz;
  long zB = (long)bzi * sBz;
  long zC = (long)bzi * sCz;
  const u16* gA = A + zA + (size_t)bm * lda;
  const u16* gB = B + zB + (size_t)bn * ldb;

  // staging constants: thread -> (row srow/srow+64, byte col scolb) of a half
  int srow = tid >> 3;             // 0..63
  int scolb = (tid & 7) << 4;      // 0..112
  int sco = (scolb ^ ((srow & 7) << 4)) >> 1;  // swizzled src col (u16)
  size_t aO0 = (size_t)srow * lda + sco, aO1 = aO0 + (size_t)64 * lda;
  size_t bO0 = (size_t)srow * ldb + sco, bO1 = bO0 + (size_t)64 * ldb;
  int ld0 = srow * 64 + (scolb >> 1), ld1 = ld0 + 64 * 64;

  auto stgA = [&](int slot, int half, int kofs) {
    const u16* g = gA + (size_t)(half * 128) * lda + kofs;
    u16* l = &sA[slot][half * 8192];
    async_stage16(g + aO0, l + ld0);
    async_stage16(g + aO1, l + ld1);
  };
  auto stgB = [&](int slot, int half, int kofs) {
    const u16* g = gB + (size_t)(half * 128) * ldb + kofs;
    u16* l = &sB[slot][half * 8192];
    async_stage16(g + bO0, l + ld0);
    async_stage16(g + bO1, l + ld1);
  };

  // fragment reads (swizzled)
  int la = lane & 15;
  int kg = (lane >> 4) << 4;
  auto frag = [&](const u16* base, int row, int colb) -> f16x8 {
    int off = (row << 7) + (colb ^ ((row & 7) << 4));
    return *reinterpret_cast<const f16x8*>(
        reinterpret_cast<const char*>(base) + off);
  };

  f16x8 aF0[4][2], aF1[4][2];
  f16x8 bF0[2][2], bF1[2][2];
  f32x4 acc[8][NB * 2] = {};

  auto RA = [&](int slot, int qm, f16x8(&dst)[4][2]) {
#pragma unroll
    for (int j = 0; j < 4; ++j)
#pragma unroll
      for (int ks = 0; ks < 2; ++ks)
        dst[j][ks] = frag(sA[slot], qm * 128 + (j * 2 + wm) * 16 + la,
                          ks * 64 + kg);
  };
  auto RB = [&](int slot, int qn, f16x8(&dst)[2][2]) {
#pragma unroll
    for (int i = 0; i < 2; ++i)
#pragma unroll
      for (int ks = 0; ks < 2; ++ks)
        dst[i][ks] = frag(sB[slot], qn * 128 + (i * 4 + wn) * 16 + la,
                          ks * 64 + kg);
  };
  auto MM = [&](int qm, int qn, f16x8(&a)[4][2], f16x8(&b)[2][2]) {
#pragma unroll
    for (int ks = 0; ks < 2; ++ks)
#pragma unroll
      for (int j = 0; j < 4; ++j)
#pragma unroll
        for (int i = 0; i < 2; ++i)
          acc[qm * 4 + j][qn * 2 + i] = __builtin_amdgcn_mfma_f32_16x16x32_f16(
              a[j][ks], b[i][ks], acc[qm * 4 + j][qn * 2 + i], 0, 0, 0);
  };

#define VM6 asm volatile("s_waitcnt vmcnt(6)" ::: "memory")
#define VM4 asm volatile("s_waitcnt vmcnt(4)" ::: "memory")
#define VM0 asm volatile("s_waitcnt vmcnt(0)" ::: "memory")
#define BAR __builtin_amdgcn_s_barrier()
#define PRIO1 __builtin_amdgcn_s_setprio(1)
#define PRIO0 __builtin_amdgcn_s_setprio(0)

  int NT = K >> 6;  // K-tiles

  if constexpr (NB == 2) {
    // ---- r11 4-phase read-ahead path ----
    stgA(0, 0, 0); stgB(0, 0, 0); stgB(0, 1, 0); stgA(0, 1, 0);
    if (NT > 1) { stgA(1, 0, 64); stgB(1, 1, 64); stgA(1, 1, 64); }
    VM6;
    BAR;
    for (int t = 0; t < NT; ++t) {
      int s = t & 1, ns = s ^ 1;
      int k1 = (t + 1) << 6, k2 = (t + 2) << 6;
      bool p1 = (t + 1 < NT), p2 = (t + 2 < NT);
      RA(s, 0, aF0); RB(s, 0, bF0);
      RB(s, 1, bF1);
      if (p1) stgB(ns, 0, k1);
      PRIO1; MM(0, 0, aF0, bF0); PRIO0; BAR;
      RA(s, 1, aF1);
      if (p2) stgA(s, 0, k2);
      PRIO1; MM(0, 1, aF0, bF1); PRIO0; BAR;
      if (p2) stgB(s, 1, k2);
      PRIO1; MM(1, 1, aF1, bF1); PRIO0; BAR;
      if (p2) stgA(s, 1, k2);
      PRIO1; MM(1, 0, aF1, bF0); PRIO0;
      if (t < NT - 2) { VM6; } else if (t == NT - 2) { VM0; }
      BAR;
    }
  } else {
    // ---- r13 NB=1 2-phase path (256-block PV) ----
    stgB(0, 0, 0); stgA(0, 0, 0); stgA(0, 1, 0);
    if (NT > 1) { stgB(1, 0, 64); stgA(1, 0, 64); }
    VM4;
    BAR;
    for (int t = 0; t < NT; ++t) {
      int s = t & 1, ns = s ^ 1;
      int k1 = (t + 1) << 6, k2 = (t + 2) << 6;
      bool p1 = (t + 1 < NT), p2 = (t + 2 < NT);
      RA(s, 0, aF0); RB(s, 0, bF0);
      RA(s, 1, aF1);
      if (p1) stgA(ns, 1, k1);
      PRIO1; MM(0, 0, aF0, bF0); PRIO0; BAR;
      if (p2) { stgB(s, 0, k2); stgA(s, 0, k2); }
      PRIO1; MM(1, 0, aF1, bF0); PRIO0;
      if (t < NT - 2) { VM4; } else if (t == NT - 2) { VM0; }
      BAR;
    }
  }
#undef VM6
#undef VM4
#undef VM0
#undef BAR
#undef PRIO1
#undef PRIO0

  // Epilogue. C/D layout (16x16): col = lane&15, row = (lane>>4)*4 + reg.
#pragma unroll
  for (int mf = 0; mf < 8; ++mf) {
    int qm = mf >> 2, j = mf & 3;
    int row = bm + qm * 128 + (j * 2 + wm) * 16 + (lane >> 4) * 4;
#pragma unroll
    for (int nf = 0; nf < NB * 2; ++nf) {
      int qn = nf >> 1, i = nf & 1;
      int col = bn + qn * 128 + (i * 4 + wn) * 16 + la;
#pragma unroll
      for (int r = 0; r < 4; ++r) {
        float v = acc[mf][nf][r];
        if constexpr (OM == 1) {
          Ch[zC + (size_t)(row + r) * ldc + col] = f2h(v + bias[col]);
        } else {
          Cf[zC + (size_t)(row + r) * ldc + col] = v;
        }
      }
    }
  }
}

// ---------- row softmax: fp32 [rows][2048] -> fp16 (pitch opitch u16) -----
__global__ __launch_bounds__(256) void softmax_kernel(const float* __restrict__ sc,
                                                      u16* __restrict__ attn,
                                                      int opitch) {
  __shared__ float red[4];
  size_t row = blockIdx.x;
  const float* p = sc + row * S_;
  u16* o = attn + row * (size_t)opitch;
  int t = threadIdx.x;
  float4 v0 = reinterpret_cast<const float4*>(p)[t];
  float4 v1 = reinterpret_cast<const float4*>(p)[t + 256];
  float mx = fmaxf(fmaxf(fmaxf(v0.x, v0.y), fmaxf(v0.z, v0.w)),
                   fmaxf(fmaxf(v1.x, v1.y), fmaxf(v1.z, v1.w)));
#pragma unroll
  for (int d = 32; d > 0; d >>= 1) mx = fmaxf(mx, __shfl_xor(mx, d));
  if ((t & 63) == 0) red[t >> 6] = mx;
  __syncthreads();
  mx = fmaxf(fmaxf(red[0], red[1]), fmaxf(red[2], red[3]));
  float e[8];
  e[0] = __expf(v0.x - mx); e[1] = __expf(v0.y - mx);
  e[2] = __expf(v0.z - mx); e[3] = __expf(v0.w - mx);
  e[4] = __expf(v1.x - mx); e[5] = __expf(v1.y - mx);
  e[6] = __expf(v1.z - mx); e[7] = __expf(v1.w - mx);
  float s = ((e[0] + e[1]) + (e[2] + e[3])) + ((e[4] + e[5]) + (e[6] + e[7]));
#pragma unroll
  for (int d = 32; d > 0; d >>= 1) s += __shfl_xor(s, d);
  __syncthreads();
  if ((t & 63) == 0) red[t >> 6] = s;
  __syncthreads();
  s = (red[0] + red[1]) + (red[2] + red[3]);
  float inv = 1.0f / s;
  ushort4 h0, h1;
  h0.x = f2h(e[0] * inv); h0.y = f2h(e[1] * inv);
  h0.z = f2h(e[2] * inv); h0.w = f2h(e[3] * inv);
  h1.x = f2h(e[4] * inv); h1.y = f2h(e[5] * inv);
  h1.z = f2h(e[6] * inv); h1.w = f2h(e[7] * inv);
  // all reads happened before the syncthreads above -> in-place safe
  reinterpret_cast<ushort4*>(o)[t] = h0;
  reinterpret_cast<ushort4*>(o)[t + 256] = h1;
}

extern "C" void kernel_launch(void* const* d_in, const int* in_sizes, int n_in,
                              void* d_out, int out_size, void* d_ws, size_t ws_size,
                              hipStream_t stream) {
  const float* X = (const float*)d_in[0];     // [8,2048,1024] fp32
  const float* W = (const float*)d_in[1];     // [1024,1024] fp32 (out,in)
  const float* bias = (const float*)d_in[2];  // [1024] fp32
  float* out = (float*)d_out;
  char* ws = (char*)d_ws;

  const size_t MB = 1ull << 20;
  u16* XF = (u16*)(ws);               // 32MB [16384][1024] fp16
  u16* WF = (u16*)(ws + 32 * MB);     // 2MB
  u16* XT = (u16*)(ws + 34 * MB);     // 32MB [b][1024][2048] fp16
  u16* QW = (u16*)(ws + 66 * MB);     // 32MB [16384][1024] fp16
  float* SC = (float*)(ws + 98 * MB); // CB*16MB fp32 scores (P in-place fp16)

  int CB = (ws_size >= 163 * MB) ? 4 : 2;
  int nch = B_ / CB;

  // 1) W -> fp16
  f32_to_f16_kernel<<<1024, 256, 0, stream>>>(W, WF, H_ * H_ / 4);
  // 2) fused: XF = fp16(X); XT[b][h][s] = fp16(X[b][s][h])
  transpose_f32_kernel<<<dim3(S_ / 64, H_ / 64, B_), 256, 0, stream>>>(
      X, XT, XF);
  // 3) QW = X @ W^T + b -> fp16  (grid 64x4 = 256 blocks)
  gemm8_kernel<1, 2><<<dim3(M_ / 256, H_ / 256, 1), 512, 0, stream>>>(
      XF, WF, nullptr, QW, bias, H_, H_, H_, H_, 0, 0, 0);
  // 4-6) per chunk: score (8x8xCB) -> softmax -> PV (8x8xCB, NB=1)
  for (int ch = 0; ch < nch; ++ch) {
    long off = (long)ch * CB;
    gemm8_kernel<0, 2><<<dim3(S_ / 256, S_ / 256, CB), 512, 0, stream>>>(
        QW + off * S_ * H_, XF + off * S_ * H_, SC, nullptr, nullptr,
        H_, H_, S_, H_, (long)S_ * H_, (long)S_ * H_, (long)S_ * S_);
    softmax_kernel<<<CB * S_, 256, 0, stream>>>(SC, (u16*)SC, 2 * S_);
    gemm8_kernel<0, 1><<<dim3(S_ / 256, H_ / 128, CB), 512, 0, stream>>>(
        (u16*)SC, XT + off * (long)H_ * S_,
        out + off * (long)S_ * H_, nullptr, nullptr,
        2 * S_, S_, H_, S_, (long)S_ * 2 * S_, (long)H_ * S_, (long)S_ * H_);
  }
}

// Round 16
// 258.772 us; speedup vs baseline: 1.1446x; 1.0214x over previous
//
#include <hip/hip_runtime.h>
#include <hip/hip_bf16.h>
#include <hip/hip_fp16.h>

typedef unsigned short u16;
typedef __attribute__((ext_vector_type(8))) _Float16 f16x8;  // 8 fp16 = 4 VGPR
typedef __attribute__((ext_vector_type(4))) float f32x4;     // MFMA 16x16 acc

#define B_ 8
#define S_ 2048
#define H_ 1024
#define M_ (B_ * S_)   // 16384

__device__ __forceinline__ u16 f2h(float f) {
  _Float16 h = (_Float16)f;
  return __builtin_bit_cast(u16, h);
}

// ---------- convert fp32 -> fp16 (W only) ----------
__global__ void f32_to_f16_kernel(const float* __restrict__ x,
                                  u16* __restrict__ o, int n4) {
  int stride = gridDim.x * blockDim.x;
  for (int i = blockIdx.x * blockDim.x + threadIdx.x; i < n4; i += stride) {
    float4 v = reinterpret_cast<const float4*>(x)[i];
    ushort4 h;
    h.x = f2h(v.x); h.y = f2h(v.y); h.z = f2h(v.z); h.w = f2h(v.w);
    reinterpret_cast<ushort4*>(o)[i] = h;
  }
}

// ---------- fused: X fp32 [b][s][h] -> XT fp16 [b][h][s] AND XF fp16 -------
// r16: BOTH phases coalesced. Read phase: 16 consecutive lanes cover ONE
// row (16 x float4 = 256B contiguous; 4 rows/wave/iter) — fixes r15's
// 4KB-stride per-lane fan-out (64 sub-line VMEM requests per load inst).
// XF store likewise 128B-contiguous per row. Write phase (r14): 16-lane
// groups emit contiguous 128B spans of one XT row. LDS pad 66 u16.
__global__ __launch_bounds__(256) void transpose_f32_kernel(
    const float* __restrict__ x, u16* __restrict__ xt, u16* __restrict__ xf) {
  __shared__ u16 t[64][66];
  int b = blockIdx.z, s0 = blockIdx.x * 64, h0 = blockIdx.y * 64;
  int tid = threadIdx.x;
  int rq = tid >> 4;        // row-group 0..15
  int cq = (tid & 15) * 4;  // float col 0..60
#pragma unroll
  for (int it = 0; it < 4; ++it) {
    int row = it * 16 + rq;
    const float* src = x + ((size_t)(b * S_ + s0 + row)) * H_ + h0 + cq;
    float4 v = *reinterpret_cast<const float4*>(src);
    ushort4 h;
    h.x = f2h(v.x); h.y = f2h(v.y); h.z = f2h(v.z); h.w = f2h(v.w);
    u16* dstf = xf + ((size_t)(b * S_ + s0 + row)) * H_ + h0 + cq;
    *reinterpret_cast<ushort4*>(dstf) = h;
    *reinterpret_cast<ushort4*>(&t[row][cq]) = h;
  }
  __syncthreads();
  int hq = tid >> 4;        // 0..15
  int sq = (tid & 15) * 4;  // s-quad 0..60
#pragma unroll
  for (int it = 0; it < 4; ++it) {
    int hh = it * 16 + hq;
    ushort4 o;
    o.x = t[sq + 0][hh];
    o.y = t[sq + 1][hh];
    o.z = t[sq + 2][hh];
    o.w = t[sq + 3][hh];
    u16* dst = xt + ((size_t)(b * H_ + h0 + hh)) * S_ + s0 + sq;
    *reinterpret_cast<ushort4*>(dst) = o;
  }
}

// ---------- async global->LDS 16B ----------
__device__ __forceinline__ void async_stage16(const u16* g, u16* l) {
  __builtin_amdgcn_global_load_lds(
      (__attribute__((address_space(1))) void*)g,
      (__attribute__((address_space(3))) void*)l, 16, 0, 0);
}

// ---------- 256x(NB*128)x64 fp16 BT-GEMM (r11 NB=2 + r13 NB=1, proven) ----
template <int OM, int NB>  // OM: 0 fp32 out; 1 fp16 out + bias
__global__ __launch_bounds__(512) void gemm8_kernel(
    const u16* __restrict__ A, const u16* __restrict__ B,
    float* __restrict__ Cf, u16* __restrict__ Ch,
    const float* __restrict__ bias,
    int lda, int ldb, int ldc, int K,
    long sAz, long sBz, long sCz) {
  __shared__ __align__(16) u16 sA[2][256 * 64];
  __shared__ __align__(16) u16 sB[2][NB * 128 * 64];

  // ---- XCD swizzle (T1, bijective m204) ----
  int gx = gridDim.x, gy = gridDim.y;
  int nwg = gx * gy * gridDim.z;
  int wgid = blockIdx.x + gx * (blockIdx.y + gy * blockIdx.z);
  int q = nwg >> 3, r = nwg & 7;
  int xcd = wgid & 7, idx = wgid >> 3;
  int nid = (xcd < r ? xcd * (q + 1) : r * (q + 1) + (xcd - r) * q) + idx;
  int bxi = nid % gx, t2 = nid / gx;
  int byi = t2 % gy, bzi = t2 / gy;

  int tid = threadIdx.x, wave = tid >> 6, lane = tid & 63;
  int wm = wave >> 2, wn = wave & 3;
  int bm = bxi * 256, bn = byi * (NB * 128);
  long zA = (long)bzi * sAz;
  long zB = (long)bzi * sBz;
  long zC = (long)bzi * sCz;
  const u16* gA = A + zA + (size_t)bm * lda;
  const u16* gB = B + zB + (size_t)bn * ldb;

  // staging constants: thread -> (row srow/srow+64, byte col scolb) of a half
  int srow = tid >> 3;             // 0..63
  int scolb = (tid & 7) << 4;      // 0..112
  int sco = (scolb ^ ((srow & 7) << 4)) >> 1;  // swizzled src col (u16)
  size_t aO0 = (size_t)srow * lda + sco, aO1 = aO0 + (size_t)64 * lda;
  size_t bO0 = (size_t)srow * ldb + sco, bO1 = bO0 + (size_t)64 * ldb;
  int ld0 = srow * 64 + (scolb >> 1), ld1 = ld0 + 64 * 64;

  auto stgA = [&](int slot, int half, int kofs) {
    const u16* g = gA + (size_t)(half * 128) * lda + kofs;
    u16* l = &sA[slot][half * 8192];
    async_stage16(g + aO0, l + ld0);
    async_stage16(g + aO1, l + ld1);
  };
  auto stgB = [&](int slot, int half, int kofs) {
    const u16* g = gB + (size_t)(half * 128) * ldb + kofs;
    u16* l = &sB[slot][half * 8192];
    async_stage16(g + bO0, l + ld0);
    async_stage16(g + bO1, l + ld1);
  };

  // fragment reads (swizzled)
  int la = lane & 15;
  int kg = (lane >> 4) << 4;
  auto frag = [&](const u16* base, int row, int colb) -> f16x8 {
    int off = (row << 7) + (colb ^ ((row & 7) << 4));
    return *reinterpret_cast<const f16x8*>(
        reinterpret_cast<const char*>(base) + off);
  };

  f16x8 aF0[4][2], aF1[4][2];
  f16x8 bF0[2][2], bF1[2][2];
  f32x4 acc[8][NB * 2] = {};

  auto RA = [&](int slot, int qm, f16x8(&dst)[4][2]) {
#pragma unroll
    for (int j = 0; j < 4; ++j)
#pragma unroll
      for (int ks = 0; ks < 2; ++ks)
        dst[j][ks] = frag(sA[slot], qm * 128 + (j * 2 + wm) * 16 + la,
                          ks * 64 + kg);
  };
  auto RB = [&](int slot, int qn, f16x8(&dst)[2][2]) {
#pragma unroll
    for (int i = 0; i < 2; ++i)
#pragma unroll
      for (int ks = 0; ks < 2; ++ks)
        dst[i][ks] = frag(sB[slot], qn * 128 + (i * 4 + wn) * 16 + la,
                          ks * 64 + kg);
  };
  auto MM = [&](int qm, int qn, f16x8(&a)[4][2], f16x8(&b)[2][2]) {
#pragma unroll
    for (int ks = 0; ks < 2; ++ks)
#pragma unroll
      for (int j = 0; j < 4; ++j)
#pragma unroll
        for (int i = 0; i < 2; ++i)
          acc[qm * 4 + j][qn * 2 + i] = __builtin_amdgcn_mfma_f32_16x16x32_f16(
              a[j][ks], b[i][ks], acc[qm * 4 + j][qn * 2 + i], 0, 0, 0);
  };

#define VM6 asm volatile("s_waitcnt vmcnt(6)" ::: "memory")
#define VM4 asm volatile("s_waitcnt vmcnt(4)" ::: "memory")
#define VM0 asm volatile("s_waitcnt vmcnt(0)" ::: "memory")
#define BAR __builtin_amdgcn_s_barrier()
#define PRIO1 __builtin_amdgcn_s_setprio(1)
#define PRIO0 __builtin_amdgcn_s_setprio(0)

  int NT = K >> 6;  // K-tiles

  if constexpr (NB == 2) {
    // ---- r11 4-phase read-ahead path ----
    stgA(0, 0, 0); stgB(0, 0, 0); stgB(0, 1, 0); stgA(0, 1, 0);
    if (NT > 1) { stgA(1, 0, 64); stgB(1, 1, 64); stgA(1, 1, 64); }
    VM6;
    BAR;
    for (int t = 0; t < NT; ++t) {
      int s = t & 1, ns = s ^ 1;
      int k1 = (t + 1) << 6, k2 = (t + 2) << 6;
      bool p1 = (t + 1 < NT), p2 = (t + 2 < NT);
      RA(s, 0, aF0); RB(s, 0, bF0);
      RB(s, 1, bF1);
      if (p1) stgB(ns, 0, k1);
      PRIO1; MM(0, 0, aF0, bF0); PRIO0; BAR;
      RA(s, 1, aF1);
      if (p2) stgA(s, 0, k2);
      PRIO1; MM(0, 1, aF0, bF1); PRIO0; BAR;
      if (p2) stgB(s, 1, k2);
      PRIO1; MM(1, 1, aF1, bF1); PRIO0; BAR;
      if (p2) stgA(s, 1, k2);
      PRIO1; MM(1, 0, aF1, bF0); PRIO0;
      if (t < NT - 2) { VM6; } else if (t == NT - 2) { VM0; }
      BAR;
    }
  } else {
    // ---- r13 NB=1 2-phase path (256-block PV) ----
    stgB(0, 0, 0); stgA(0, 0, 0); stgA(0, 1, 0);
    if (NT > 1) { stgB(1, 0, 64); stgA(1, 0, 64); }
    VM4;
    BAR;
    for (int t = 0; t < NT; ++t) {
      int s = t & 1, ns = s ^ 1;
      int k1 = (t + 1) << 6, k2 = (t + 2) << 6;
      bool p1 = (t + 1 < NT), p2 = (t + 2 < NT);
      RA(s, 0, aF0); RB(s, 0, bF0);
      RA(s, 1, aF1);
      if (p1) stgA(ns, 1, k1);
      PRIO1; MM(0, 0, aF0, bF0); PRIO0; BAR;
      if (p2) { stgB(s, 0, k2); stgA(s, 0, k2); }
      PRIO1; MM(1, 0, aF1, bF0); PRIO0;
      if (t < NT - 2) { VM4; } else if (t == NT - 2) { VM0; }
      BAR;
    }
  }
#undef VM6
#undef VM4
#undef VM0
#undef BAR
#undef PRIO1
#undef PRIO0

  // Epilogue. C/D layout (16x16): col = lane&15, row = (lane>>4)*4 + reg.
#pragma unroll
  for (int mf = 0; mf < 8; ++mf) {
    int qm = mf >> 2, j = mf & 3;
    int row = bm + qm * 128 + (j * 2 + wm) * 16 + (lane >> 4) * 4;
#pragma unroll
    for (int nf = 0; nf < NB * 2; ++nf) {
      int qn = nf >> 1, i = nf & 1;
      int col = bn + qn * 128 + (i * 4 + wn) * 16 + la;
#pragma unroll
      for (int r = 0; r < 4; ++r) {
        float v = acc[mf][nf][r];
        if constexpr (OM == 1) {
          Ch[zC + (size_t)(row + r) * ldc + col] = f2h(v + bias[col]);
        } else {
          Cf[zC + (size_t)(row + r) * ldc + col] = v;
        }
      }
    }
  }
}

// ---------- row softmax: fp32 [rows][2048] -> fp16 (pitch opitch u16) -----
__global__ __launch_bounds__(256) void softmax_kernel(const float* __restrict__ sc,
                                                      u16* __restrict__ attn,
                                                      int opitch) {
  __shared__ float red[4];
  size_t row = blockIdx.x;
  const float* p = sc + row * S_;
  u16* o = attn + row * (size_t)opitch;
  int t = threadIdx.x;
  float4 v0 = reinterpret_cast<const float4*>(p)[t];
  float4 v1 = reinterpret_cast<const float4*>(p)[t + 256];
  float mx = fmaxf(fmaxf(fmaxf(v0.x, v0.y), fmaxf(v0.z, v0.w)),
                   fmaxf(fmaxf(v1.x, v1.y), fmaxf(v1.z, v1.w)));
#pragma unroll
  for (int d = 32; d > 0; d >>= 1) mx = fmaxf(mx, __shfl_xor(mx, d));
  if ((t & 63) == 0) red[t >> 6] = mx;
  __syncthreads();
  mx = fmaxf(fmaxf(red[0], red[1]), fmaxf(red[2], red[3]));
  float e[8];
  e[0] = __expf(v0.x - mx); e[1] = __expf(v0.y - mx);
  e[2] = __expf(v0.z - mx); e[3] = __expf(v0.w - mx);
  e[4] = __expf(v1.x - mx); e[5] = __expf(v1.y - mx);
  e[6] = __expf(v1.z - mx); e[7] = __expf(v1.w - mx);
  float s = ((e[0] + e[1]) + (e[2] + e[3])) + ((e[4] + e[5]) + (e[6] + e[7]));
#pragma unroll
  for (int d = 32; d > 0; d >>= 1) s += __shfl_xor(s, d);
  __syncthreads();
  if ((t & 63) == 0) red[t >> 6] = s;
  __syncthreads();
  s = (red[0] + red[1]) + (red[2] + red[3]);
  float inv = 1.0f / s;
  ushort4 h0, h1;
  h0.x = f2h(e[0] * inv); h0.y = f2h(e[1] * inv);
  h0.z = f2h(e[2] * inv); h0.w = f2h(e[3] * inv);
  h1.x = f2h(e[4] * inv); h1.y = f2h(e[5] * inv);
  h1.z = f2h(e[6] * inv); h1.w = f2h(e[7] * inv);
  // all reads happened before the syncthreads above -> in-place safe
  reinterpret_cast<ushort4*>(o)[t] = h0;
  reinterpret_cast<ushort4*>(o)[t + 256] = h1;
}

extern "C" void kernel_launch(void* const* d_in, const int* in_sizes, int n_in,
                              void* d_out, int out_size, void* d_ws, size_t ws_size,
                              hipStream_t stream) {
  const float* X = (const float*)d_in[0];     // [8,2048,1024] fp32
  const float* W = (const float*)d_in[1];     // [1024,1024] fp32 (out,in)
  const float* bias = (const float*)d_in[2];  // [1024] fp32
  float* out = (float*)d_out;
  char* ws = (char*)d_ws;

  const size_t MB = 1ull << 20;
  u16* XF = (u16*)(ws);               // 32MB [16384][1024] fp16
  u16* WF = (u16*)(ws + 32 * MB);     // 2MB
  u16* XT = (u16*)(ws + 34 * MB);     // 32MB [b][1024][2048] fp16
  u16* QW = (u16*)(ws + 66 * MB);     // 32MB [16384][1024] fp16
  float* SC = (float*)(ws + 98 * MB); // CB*16MB fp32 scores (P in-place fp16)

  int CB = (ws_size >= 163 * MB) ? 4 : 2;
  int nch = B_ / CB;

  // 1) W -> fp16
  f32_to_f16_kernel<<<1024, 256, 0, stream>>>(W, WF, H_ * H_ / 4);
  // 2) fused: XF = fp16(X); XT[b][h][s] = fp16(X[b][s][h])
  transpose_f32_kernel<<<dim3(S_ / 64, H_ / 64, B_), 256, 0, stream>>>(
      X, XT, XF);
  // 3) QW = X @ W^T + b -> fp16  (grid 64x4 = 256 blocks)
  gemm8_kernel<1, 2><<<dim3(M_ / 256, H_ / 256, 1), 512, 0, stream>>>(
      XF, WF, nullptr, QW, bias, H_, H_, H_, H_, 0, 0, 0);
  // 4-6) per chunk: score (8x8xCB) -> softmax -> PV (8x8xCB, NB=1)
  for (int ch = 0; ch < nch; ++ch) {
    long off = (long)ch * CB;
    gemm8_kernel<0, 2><<<dim3(S_ / 256, S_ / 256, CB), 512, 0, stream>>>(
        QW + off * S_ * H_, XF + off * S_ * H_, SC, nullptr, nullptr,
        H_, H_, S_, H_, (long)S_ * H_, (long)S_ * H_, (long)S_ * S_);
    softmax_kernel<<<CB * S_, 256, 0, stream>>>(SC, (u16*)SC, 2 * S_);
    gemm8_kernel<0, 1><<<dim3(S_ / 256, H_ / 128, CB), 512, 0, stream>>>(
        (u16*)SC, XT + off * (long)H_ * S_,
        out + off * (long)S_ * H_, nullptr, nullptr,
        2 * S_, S_, H_, S_, (long)S_ * 2 * S_, (long)H_ * S_, (long)S_ * H_);
  }
}